// Round 1
// baseline (8059.433 us; speedup 1.0000x reference)
//
#include <hip/hip_runtime.h>
#include <cstdint>
#include <cmath>

#define S_LEN 1024
#define BATCH 64
#define IN_SZ 256
#define HID 512
#define OUT_SZ 256
#define WIH_LD 768  // W_ih leading dim = IN_SZ + HID

// ws layout (floats):
//  [0, 33554432)            xp / hidden_seq, layout [s][b][h]  (128 MB)
//  [33554432, 33816576)     Wh^T packed for float4 loads       (1 MB)
#define XP_FLOATS (S_LEN * BATCH * HID)

// whp[(k>>2)*2048 + j*4 + (k&3)] = Wh[j][k] = W_ih[j][256+k]
// so (float4)whp4[k4*512 + j] = {Wh[j][4k4..4k4+3]}
__global__ __launch_bounds__(256) void pack_wht(const float* __restrict__ W_ih,
                                                float* __restrict__ whp) {
    int g = blockIdx.x * 256 + threadIdx.x;   // 0..262143
    int kg = g >> 11;           // k group (k/4): 0..127
    int j  = (g >> 2) & 511;
    int kl = g & 3;
    int k  = (kg << 2) + kl;
    whp[g] = W_ih[(size_t)j * WIH_LD + IN_SZ + k];
}

// xp[s][b][h] = dot(x[b][s][:], W_ih[h][0:256]) + b_ih[h]
// grid (1024, 8): block = one s (64 b's) x 64 h's. 256 threads, 4x4 acc each.
__global__ __launch_bounds__(256) void xproj(const float* __restrict__ x,
                                             const float* __restrict__ W_ih,
                                             const float* __restrict__ b_ih,
                                             float* __restrict__ xp) {
    __shared__ float As[16][64];   // As[k][b]
    __shared__ float Bs[16][64];   // Bs[k][h]
    const int s   = blockIdx.x;
    const int nb  = blockIdx.y * 64;
    const int tid = threadIdx.x;
    const int lm  = tid >> 2;          // 0..63 (row to load)
    const int lk  = (tid & 3) << 2;    // 0,4,8,12
    const int mr  = (tid & 15) << 2;   // b sub-tile
    const int nr  = (tid >> 4) << 2;   // h sub-tile
    float acc[4][4] = {};
    for (int k0 = 0; k0 < IN_SZ; k0 += 16) {
        float4 av = *(const float4*)(x + ((size_t)lm * S_LEN + s) * IN_SZ + k0 + lk);
        float4 bv = *(const float4*)(W_ih + (size_t)(nb + lm) * WIH_LD + k0 + lk);
        __syncthreads();
        As[lk + 0][lm] = av.x; As[lk + 1][lm] = av.y;
        As[lk + 2][lm] = av.z; As[lk + 3][lm] = av.w;
        Bs[lk + 0][lm] = bv.x; Bs[lk + 1][lm] = bv.y;
        Bs[lk + 2][lm] = bv.z; Bs[lk + 3][lm] = bv.w;
        __syncthreads();
#pragma unroll
        for (int kk = 0; kk < 16; ++kk) {
            float4 a = *(const float4*)&As[kk][mr];
            float4 b = *(const float4*)&Bs[kk][nr];
            float aa[4] = {a.x, a.y, a.z, a.w};
            float bb[4] = {b.x, b.y, b.z, b.w};
#pragma unroll
            for (int i = 0; i < 4; ++i)
#pragma unroll
                for (int j = 0; j < 4; ++j) acc[i][j] += aa[i] * bb[j];
        }
    }
#pragma unroll
    for (int i = 0; i < 4; ++i) {
        int b = mr + i;
        int h = nb + nr;
        float4 o;
        o.x = acc[i][0] + b_ih[h + 0];
        o.y = acc[i][1] + b_ih[h + 1];
        o.z = acc[i][2] + b_ih[h + 2];
        o.w = acc[i][3] + b_ih[h + 3];
        *(float4*)(xp + (size_t)s * (BATCH * HID) + (size_t)b * HID + h) = o;
    }
}

// One WG per batch element. h kept in LDS; xp overwritten in place with h_t.
__global__ __launch_bounds__(512) void rnn_rec(const float4* __restrict__ whp4,
                                               float* __restrict__ xp) {
    const int b = blockIdx.x;
    const int j = threadIdx.x;
    __shared__ float h[HID];
    h[j] = 0.f;
    __syncthreads();
    float* col = xp + (size_t)b * HID + j;
    for (int s = 0; s < S_LEN; ++s) {
        float acc = col[(size_t)s * (BATCH * HID)];
#pragma unroll 8
        for (int k4 = 0; k4 < HID / 4; ++k4) {
            float4 w  = whp4[(size_t)k4 * HID + j];
            float4 hv = *(const float4*)&h[k4 << 2];
            acc += w.x * hv.x + w.y * hv.y + w.z * hv.z + w.w * hv.w;
        }
        float hn = tanhf(acc);
        __syncthreads();           // all reads of h done
        h[j] = hn;
        col[(size_t)s * (BATCH * HID)] = hn;
        __syncthreads();           // h updated before next step reads
    }
}

// Per-batch fused: scores -> softmax -> context -> out = ctx @ W_ho^T + b_ho
__global__ __launch_bounds__(256) void attn_out(const float* __restrict__ hbuf,
                                                const float* __restrict__ W_ho,
                                                const float* __restrict__ b_ho,
                                                float* __restrict__ out) {
    const int b    = blockIdx.x;
    const int tid  = threadIdx.x;
    const int lane = tid & 63;
    const int wave = tid >> 6;   // 4 waves
    __shared__ float fh[HID];
    __shared__ float sc[S_LEN];
    __shared__ float red[4];
    __shared__ float ctx[HID];
    // final hidden
    for (int k = tid; k < HID; k += 256)
        fh[k] = hbuf[(size_t)(S_LEN - 1) * BATCH * HID + (size_t)b * HID + k];
    __syncthreads();
    // scores: one wave per s
    for (int s = wave; s < S_LEN; s += 4) {
        const float* hr = hbuf + (size_t)s * BATCH * HID + (size_t)b * HID;
        float p = 0.f;
#pragma unroll
        for (int k = lane; k < HID; k += 64) p += hr[k] * fh[k];
#pragma unroll
        for (int off = 32; off; off >>= 1) p += __shfl_down(p, off, 64);
        if (lane == 0) sc[s] = p;
    }
    __syncthreads();
    // softmax over S in LDS
    float m = -1e30f;
    for (int s2 = tid; s2 < S_LEN; s2 += 256) m = fmaxf(m, sc[s2]);
#pragma unroll
    for (int off = 32; off; off >>= 1) m = fmaxf(m, __shfl_down(m, off, 64));
    if (lane == 0) red[wave] = m;
    __syncthreads();
    m = fmaxf(fmaxf(red[0], red[1]), fmaxf(red[2], red[3]));
    float sum = 0.f;
    for (int s2 = tid; s2 < S_LEN; s2 += 256) {
        float e = expf(sc[s2] - m);
        sc[s2] = e;
        sum += e;
    }
#pragma unroll
    for (int off = 32; off; off >>= 1) sum += __shfl_down(sum, off, 64);
    __syncthreads();             // everyone done reading red (max) + sc writes visible
    if (lane == 0) red[wave] = sum;
    __syncthreads();
    sum = red[0] + red[1] + red[2] + red[3];
    const float inv = 1.f / sum;
    // context: thread covers h = tid and tid+256
    float c0 = 0.f, c1 = 0.f;
    for (int s2 = 0; s2 < S_LEN; ++s2) {
        const float* hr = hbuf + (size_t)s2 * BATCH * HID + (size_t)b * HID;
        float a = sc[s2] * inv;
        c0 += a * hr[tid];
        c1 += a * hr[tid + 256];
    }
    ctx[tid] = c0;
    ctx[tid + 256] = c1;
    __syncthreads();
    // out[b][o], one thread per o
    float oacc = b_ho[tid];
    const float* wr = W_ho + (size_t)tid * HID;
#pragma unroll 4
    for (int k = 0; k < HID; ++k) oacc += wr[k] * ctx[k];
    out[(size_t)b * OUT_SZ + tid] = oacc;
}

extern "C" void kernel_launch(void* const* d_in, const int* in_sizes, int n_in,
                              void* d_out, int out_size, void* d_ws, size_t ws_size,
                              hipStream_t stream) {
    const float* x    = (const float*)d_in[0];
    const float* W_ih = (const float*)d_in[1];
    const float* b_ih = (const float*)d_in[2];
    const float* W_ho = (const float*)d_in[3];
    const float* b_ho = (const float*)d_in[4];
    float* out = (float*)d_out;
    float* ws  = (float*)d_ws;

    float* xp  = ws;                 // 33,554,432 floats (in-place hidden_seq)
    float* whp = ws + XP_FLOATS;     // 262,144 floats

    pack_wht<<<dim3(1024), dim3(256), 0, stream>>>(W_ih, whp);
    xproj<<<dim3(1024, 8), dim3(256), 0, stream>>>(x, W_ih, b_ih, xp);
    rnn_rec<<<dim3(64), dim3(512), 0, stream>>>((const float4*)whp, xp);
    attn_out<<<dim3(64), dim3(256), 0, stream>>>(xp, W_ho, b_ho, out);
}